// Round 3
// baseline (223.815 us; speedup 1.0000x reference)
//
#include <hip/hip_runtime.h>

// Geometry fixed by setup_inputs: b=16, n=32, h=w=256.
#define B 16
#define N 32
#define HW 65536             // 256*256
#define CHUNKS 8             // chunks per (b,n) pair
#define CHUNK (HW / CHUNKS)  // 8192 elements per block
#define PAIRS (B * N)        // 512
#define NBLK (PAIRS * CHUNKS) // 4096 blocks
#define EPS 1e-6f

// ws layout: [0 .. PAIRS) float2 accumulators (4096 B), then u32 ticket counter.

__global__ __launch_bounds__(256, 4) void iou_fused_kernel(
    const float* __restrict__ pd, const float* __restrict__ gt,
    const int* __restrict__ pdm, const int* __restrict__ gtm,
    float* __restrict__ ws, unsigned int* __restrict__ cnt,
    float* __restrict__ out)
{
    // XCD-chunked bijective swizzle: hw block i (XCD = i%8) -> orig (i%8)*512 + i/8,
    // so each XCD owns a contiguous 512-orig-block range = 2 b-values (pd/gt L2-resident).
    const int blk   = (blockIdx.x & 7) * (NBLK / 8) + (blockIdx.x >> 3);
    const int pair  = blk >> 3;          // b*N + n
    const int chunk = blk & 7;
    const int b     = pair >> 5;
    const int t     = threadIdx.x;

    const int base = chunk * CHUNK;
    const float4* __restrict__ pdp = (const float4*)(pd + (size_t)b * HW + base);
    const float4* __restrict__ gtp = (const float4*)(gt + (size_t)b * HW + base);
    const int4*   __restrict__ pmp = (const int4*)(pdm + (size_t)pair * HW + base);
    const int4*   __restrict__ gmp = (const int4*)(gtm + (size_t)pair * HW + base);

    float inter = 0.0f, uni = 0.0f;

    // CHUNK/4 = 2048 float4 per stream, 256 threads -> 8 per thread.
    // Same load structure as the 49us R1 kernel (batch-4 interleave).
    #pragma unroll
    for (int o = 0; o < 2; ++o) {
        float4 p[4], g[4];
        int4  pm[4], gm[4];
        #pragma unroll
        for (int u = 0; u < 4; ++u) {
            const int i = (o * 4 + u) * 256 + t;
            pm[u] = pmp[i];
            gm[u] = gmp[i];
            p[u]  = pdp[i];
            g[u]  = gtp[i];
        }
        #pragma unroll
        for (int u = 0; u < 4; ++u) {
            inter += (pm[u].x & gm[u].x) ? p[u].x : 0.0f;
            inter += (pm[u].y & gm[u].y) ? p[u].y : 0.0f;
            inter += (pm[u].z & gm[u].z) ? p[u].z : 0.0f;
            inter += (pm[u].w & gm[u].w) ? p[u].w : 0.0f;

            uni += (gm[u].x ? g[u].x : 0.0f) + ((pm[u].x & ~gm[u].x) ? p[u].x : 0.0f);
            uni += (gm[u].y ? g[u].y : 0.0f) + ((pm[u].y & ~gm[u].y) ? p[u].y : 0.0f);
            uni += (gm[u].z ? g[u].z : 0.0f) + ((pm[u].z & ~gm[u].z) ? p[u].z : 0.0f);
            uni += (gm[u].w ? g[u].w : 0.0f) + ((pm[u].w & ~gm[u].w) ? p[u].w : 0.0f);
        }
    }

    // wave64 reduce, then cross-wave via LDS
    #pragma unroll
    for (int o = 32; o > 0; o >>= 1) {
        inter += __shfl_down(inter, o, 64);
        uni   += __shfl_down(uni, o, 64);
    }

    __shared__ float s_i[4], s_u[4], s_l[4];
    __shared__ int isLast;
    const int wave = t >> 6, lane = t & 63;
    if (lane == 0) { s_i[wave] = inter; s_u[wave] = uni; }
    __syncthreads();

    if (t == 0) {
        const float I = s_i[0] + s_i[1] + s_i[2] + s_i[3];
        const float U = s_u[0] + s_u[1] + s_u[2] + s_u[3];
        // Publish via atomic RMW only — executes at the coherent point,
        // device-scope by default; NO __threadfence (R2 showed per-block
        // fences flush L2 and serialize the chip).
        atomicAdd(&ws[pair * 2 + 0], I);
        atomicAdd(&ws[pair * 2 + 1], U);
        // Ticket: release orders our atomicAdds (vmcnt drain) before it.
        const unsigned old = __hip_atomic_fetch_add(
            cnt, 1u, __ATOMIC_ACQ_REL, __HIP_MEMORY_SCOPE_AGENT);
        isLast = (old == NBLK - 1) ? 1 : 0;
    }
    __syncthreads();

    if (isLast) {  // block-uniform: exactly one block runs this
        float loss = 0.0f;
        #pragma unroll
        for (int q = t; q < PAIRS; q += 256) {
            const float I = __hip_atomic_load(&ws[q * 2 + 0],
                __ATOMIC_RELAXED, __HIP_MEMORY_SCOPE_AGENT);
            const float U = __hip_atomic_load(&ws[q * 2 + 1],
                __ATOMIC_RELAXED, __HIP_MEMORY_SCOPE_AGENT);
            loss += I / (U + EPS);
        }
        #pragma unroll
        for (int o = 32; o > 0; o >>= 1)
            loss += __shfl_down(loss, o, 64);
        if (lane == 0) s_l[wave] = loss;
        __syncthreads();
        if (t == 0)
            out[0] = 1.0f - (s_l[0] + s_l[1] + s_l[2] + s_l[3]) / (float)PAIRS;
    }
}

extern "C" void kernel_launch(void* const* d_in, const int* in_sizes, int n_in,
                              void* d_out, int out_size, void* d_ws, size_t ws_size,
                              hipStream_t stream) {
    const float* pd  = (const float*)d_in[0];
    const float* gt  = (const float*)d_in[1];
    const int*   pdm = (const int*)d_in[2];
    const int*   gtm = (const int*)d_in[3];
    float* out = (float*)d_out;

    float* ws = (float*)d_ws;                       // PAIRS*2 floats = 4096 B
    unsigned int* cnt = (unsigned int*)((char*)d_ws + PAIRS * 2 * sizeof(float));

    // accumulators + ticket must be zero at every call (ws poisoned once only)
    hipMemsetAsync(d_ws, 0, PAIRS * 2 * sizeof(float) + sizeof(unsigned int), stream);
    iou_fused_kernel<<<NBLK, 256, 0, stream>>>(pd, gt, pdm, gtm, ws, cnt, out);
}

// Round 4
// 46.435 us; speedup vs baseline: 4.8200x; 4.8200x over previous
//
#include <hip/hip_runtime.h>

// Geometry fixed by setup_inputs: b=16, n=32, h=w=256.
#define B 16
#define N 32
#define HW 65536            // 256*256
#define CHUNKS 4            // chunks per (b,n) pair
#define CHUNK (HW / CHUNKS) // 16384 elements per block
#define PAIRS (B * N)       // 512
#define NBLK (PAIRS * CHUNKS) // 2048
#define EPS 1e-6f

// Two-kernel structure (R1 = 49us). NO cross-workgroup atomics/fences:
// R2/R3 showed per-block acquire/release (ticket atomic or threadfence)
// emits L2 writeback/invalidate per block -> 4.5x regression.

__global__ __launch_bounds__(256, 4) void iou_partial_kernel(
    const float* __restrict__ pd, const float* __restrict__ gt,
    const int* __restrict__ pdm, const int* __restrict__ gtm,
    float2* __restrict__ ws)
{
    // XCD-chunked bijective swizzle (NBLK=2048 divisible by 8):
    // hw block i (on XCD i%8) -> orig (i%8)*256 + i/8, so each XCD owns a
    // contiguous 256-block range = 2 b-values -> pd/gt (1 MB) L2-resident.
    const int blk   = (blockIdx.x & 7) * (NBLK / 8) + (blockIdx.x >> 3);
    const int pair  = blk >> 2;          // b*N + n
    const int chunk = blk & 3;
    const int b     = pair >> 5;
    const int t     = threadIdx.x;

    const int base = chunk * CHUNK;
    const float4* __restrict__ pdp = (const float4*)(pd + (size_t)b * HW + base);
    const float4* __restrict__ gtp = (const float4*)(gt + (size_t)b * HW + base);
    const int4*   __restrict__ pmp = (const int4*)(pdm + (size_t)pair * HW + base);
    const int4*   __restrict__ gmp = (const int4*)(gtm + (size_t)pair * HW + base);

    float inter = 0.0f, uni = 0.0f;

    // CHUNK/4 = 4096 float4 per stream, 256 threads -> 16 iters/thread.
    // Explicit batch-4: 16 x 16B loads in flight, then consume.
    #pragma unroll
    for (int o = 0; o < 4; ++o) {
        float4 p[4], g[4];
        int4  pm[4], gm[4];
        #pragma unroll
        for (int u = 0; u < 4; ++u) {
            const int i = (o * 4 + u) * 256 + t;
            pm[u] = pmp[i];
            gm[u] = gmp[i];
            p[u]  = pdp[i];
            g[u]  = gtp[i];
        }
        #pragma unroll
        for (int u = 0; u < 4; ++u) {
            inter += (pm[u].x & gm[u].x) ? p[u].x : 0.0f;
            inter += (pm[u].y & gm[u].y) ? p[u].y : 0.0f;
            inter += (pm[u].z & gm[u].z) ? p[u].z : 0.0f;
            inter += (pm[u].w & gm[u].w) ? p[u].w : 0.0f;

            uni += (gm[u].x ? g[u].x : 0.0f) + ((pm[u].x & ~gm[u].x) ? p[u].x : 0.0f);
            uni += (gm[u].y ? g[u].y : 0.0f) + ((pm[u].y & ~gm[u].y) ? p[u].y : 0.0f);
            uni += (gm[u].z ? g[u].z : 0.0f) + ((pm[u].z & ~gm[u].z) ? p[u].z : 0.0f);
            uni += (gm[u].w ? g[u].w : 0.0f) + ((pm[u].w & ~gm[u].w) ? p[u].w : 0.0f);
        }
    }

    #pragma unroll
    for (int o = 32; o > 0; o >>= 1) {
        inter += __shfl_down(inter, o, 64);
        uni   += __shfl_down(uni, o, 64);
    }

    __shared__ float s_i[4], s_u[4];
    const int wave = t >> 6, lane = t & 63;
    if (lane == 0) { s_i[wave] = inter; s_u[wave] = uni; }
    __syncthreads();
    if (t == 0) {
        ws[blk] = make_float2(s_i[0] + s_i[1] + s_i[2] + s_i[3],
                              s_u[0] + s_u[1] + s_u[2] + s_u[3]);
    }
}

__global__ __launch_bounds__(512) void iou_final_kernel(
    const float2* __restrict__ ws, float* __restrict__ out)
{
    const int t = threadIdx.x; // one thread per pair
    float I = 0.0f, U = 0.0f;
    #pragma unroll
    for (int c = 0; c < CHUNKS; ++c) {
        float2 v = ws[t * CHUNKS + c];
        I += v.x; U += v.y;
    }
    float loss = I / (U + EPS);

    #pragma unroll
    for (int o = 32; o > 0; o >>= 1)
        loss += __shfl_down(loss, o, 64);

    __shared__ float s[8];
    const int wave = t >> 6, lane = t & 63;
    if (lane == 0) s[wave] = loss;
    __syncthreads();
    if (t == 0) {
        float sum = 0.0f;
        #pragma unroll
        for (int w = 0; w < 8; ++w) sum += s[w];
        out[0] = 1.0f - sum / (float)PAIRS;
    }
}

extern "C" void kernel_launch(void* const* d_in, const int* in_sizes, int n_in,
                              void* d_out, int out_size, void* d_ws, size_t ws_size,
                              hipStream_t stream) {
    const float* pd  = (const float*)d_in[0];
    const float* gt  = (const float*)d_in[1];
    const int*   pdm = (const int*)d_in[2];
    const int*   gtm = (const int*)d_in[3];
    float* out = (float*)d_out;
    float2* ws = (float2*)d_ws;   // NBLK float2 = 16 KB

    iou_partial_kernel<<<NBLK, 256, 0, stream>>>(pd, gt, pdm, gtm, ws);
    iou_final_kernel<<<1, 512, 0, stream>>>(ws, out);
}